// Round 16
// baseline (103.129 us; speedup 1.0000x reference)
//
#include <hip/hip_runtime.h>

#define BB 512
#define SS 512
#define TT 64
#define TSTRIDE 66   // transitions is (66,66)

typedef _Float16 h2 __attribute__((ext_vector_type(2)));
typedef int i2v __attribute__((ext_vector_type(2)));

static __device__ __forceinline__ float first_lane(float v) {
    return __int_as_float(__builtin_amdgcn_readfirstlane(__float_as_int(v)));
}
static __device__ __forceinline__ unsigned pk_f16(float a, float b) {
    return __builtin_bit_cast(unsigned, __builtin_amdgcn_cvt_pkrtz(a, b));
}
static __device__ __forceinline__ h2 as_h2(unsigned u) {
    return __builtin_bit_cast(h2, u);
}
static __device__ __forceinline__ unsigned bperm(int addr, unsigned v) {
    return (unsigned)__builtin_amdgcn_ds_bpermute(addr, (int)v);
}
static __device__ __forceinline__ float swz16f(float v) {   // value from lane^16
    return __int_as_float(__builtin_amdgcn_ds_swizzle(__float_as_int(v), 0x401F));
}
#define FDOT2(a, b, c) __builtin_amdgcn_fdot2((a), (b), (c), false)
#define DPPF(v, ctrl) __int_as_float(__builtin_amdgcn_mov_dpp(__float_as_int(v), (ctrl), 0xF, 0xF, true))
#define DPPU(v, ctrl) ((unsigned)__builtin_amdgcn_mov_dpp((int)(v), (ctrl), 0xF, 0xF, true))

#define DO32(F) F(0) F(1) F(2) F(3) F(4) F(5) F(6) F(7) \
                F(8) F(9) F(10) F(11) F(12) F(13) F(14) F(15) \
                F(16) F(17) F(18) F(19) F(20) F(21) F(22) F(23) \
                F(24) F(25) F(26) F(27) F(28) F(29) F(30) F(31)

// R16: 4-segment MITM via rank-1 segment compression. Segments:
// A = steps 1..127 (exact, from v0), B = 128..255, C = 256..383,
// D = 511..384 (exact, from stop). B and C are rank-1 to f32 precision
// (Birkhoff: each E-application contracts projective metric by ~0.1;
// 128 steps => 1e-128): M ~ (Mu)(M^T u)^T / (u^T M u), so each needs only
// fwd-from-ones and bwd-from-ones VECTOR chains. 6 chains/batch, 128 steps
// each, 3072 waves = 3/SIMD (132 VGPR allows 3.87). Step skeleton = R15
// (absmax-0 verified): product-form recurrence, blocked dots, VALU reduce.
// roles: 0=a(A-fwd,v0) 1=Bu(fwd,u) 3=Cu(fwd,u,mask) |
//        2=BTu(bwd,u) 4=CTu(bwd,u,mask) 5=d(D-bwd,stop,mask)
__global__ __launch_bounds__(64)
__attribute__((amdgpu_waves_per_eu(1, 1)))
void crf_scan6_kernel(
    const float* __restrict__ emissions,   // [B,S,T]
    const float* __restrict__ mask,        // [B,S]
    const float* __restrict__ trans,       // [66,66]
    float* __restrict__ ws_state)          // [B][6][64] log-form vectors
{
    __shared__ unsigned EQ[32][64];        // 8 KB E-fragment staging

    const int blk  = blockIdx.x;
    const int b    = blk / 6;
    const int role = blk - 6 * b;
    const bool isFwd = (role == 0) | (role == 1) | (role == 3);
    const int j   = threadIdx.x;   // 0..63
    const bool lo32  = (j < 32);
    const bool odd16 = (j & 16) != 0;
    const int a32v = ((j ^ 32) << 2);      // bpermute fallback address

    const float* em = emissions + (size_t)b * SS * TT;
    const float* mk = mask + (size_t)b * SS;

    // ---- E fragments, pre-permuted (R11-verified layout) ----
    {
        const int tl[8] = {0, 2, 7, 5, 15, 13, 8, 10};
        #pragma unroll
        for (int w = 0; w < 32; ++w) {
            int m = w >> 3, k = w & 7;
            int y0 = j ^ tl[k];
            int y1 = y0 ^ 1;
            int x  = j ^ (m << 4);
            if (isFwd)      // fwd: M[x][y] = trans[y*66 + x]
                EQ[w][j] = pk_f16(__expf(trans[y0 * TSTRIDE + x]),
                                  __expf(trans[y1 * TSTRIDE + x]));
            else            // bwd: M[x][y] = trans[x*66 + y]
                EQ[w][j] = pk_f16(__expf(trans[x * TSTRIDE + y0]),
                                  __expf(trans[x * TSTRIDE + y1]));
        }
    }
    __syncthreads();

#define CDECL(K) const unsigned c##K = EQ[K][j];
    DO32(CDECL)
#undef CDECL

#if defined(__has_builtin) && __has_builtin(__builtin_amdgcn_permlane32_swap)
#define XCH32F(DST, SRC) { i2v r_ = __builtin_amdgcn_permlane32_swap( \
                               __float_as_int(SRC), __float_as_int(SRC), false, false); \
                           DST = __int_as_float(lo32 ? r_.y : r_.x); }
#else
#define XCH32F(DST, SRC) { DST = __int_as_float((int)bperm(a32v, (unsigned)__float_as_int(SRC))); }
#endif

#if defined(__has_builtin) && __has_builtin(__builtin_amdgcn_permlane16_swap)
#define XCH16F(DST, SRC) { i2v r_ = __builtin_amdgcn_permlane16_swap( \
                               __float_as_int(SRC), __float_as_int(SRC), false, false); \
                           DST = __int_as_float(odd16 ? r_.x : r_.y); }
#else
#define XCH16F(DST, SRC) { DST = swz16f(SRC); }
#endif

    // len (all roles; masked GPREP is harmless for always-valid ranges)
    float msum = 0.f;
    #pragma unroll
    for (int tq = 0; tq < 8; ++tq) msum += mk[j + 64 * tq];
    #pragma unroll
    for (int off = 32; off; off >>= 1) msum += __shfl_xor(msum, off);
    const int len = (int)(first_lane(msum) + 0.5f);   // in [256,512]

    float t, L2 = 0.f, Lc = 0.f;

#define STEPP(GK) do { \
        float pn_ = DPPF(t, 0xB1); \
        unsigned W0 = pk_f16(t, pn_); \
        unsigned W1 = DPPU(W0, 0x4E); \
        unsigned W2 = DPPU(W0, 0x141); \
        unsigned W3 = DPPU(W1, 0x141); \
        unsigned W4 = DPPU(W0, 0x140); \
        unsigned W5 = DPPU(W1, 0x140); \
        unsigned W6 = DPPU(W4, 0x141); \
        unsigned W7 = DPPU(W5, 0x141); \
        float a0_ = 0.f, a1_ = 0.f, a2_ = 0.f, a3_ = 0.f; \
        a0_ = FDOT2(as_h2(W0), as_h2(c0),  a0_); \
        a1_ = FDOT2(as_h2(W0), as_h2(c8),  a1_); \
        a2_ = FDOT2(as_h2(W0), as_h2(c16), a2_); \
        a3_ = FDOT2(as_h2(W0), as_h2(c24), a3_); \
        a0_ = FDOT2(as_h2(W1), as_h2(c1),  a0_); \
        a1_ = FDOT2(as_h2(W1), as_h2(c9),  a1_); \
        a2_ = FDOT2(as_h2(W1), as_h2(c17), a2_); \
        a3_ = FDOT2(as_h2(W1), as_h2(c25), a3_); \
        a0_ = FDOT2(as_h2(W2), as_h2(c2),  a0_); \
        a1_ = FDOT2(as_h2(W2), as_h2(c10), a1_); \
        a2_ = FDOT2(as_h2(W2), as_h2(c18), a2_); \
        a3_ = FDOT2(as_h2(W2), as_h2(c26), a3_); \
        a0_ = FDOT2(as_h2(W3), as_h2(c3),  a0_); \
        a1_ = FDOT2(as_h2(W3), as_h2(c11), a1_); \
        a2_ = FDOT2(as_h2(W3), as_h2(c19), a2_); \
        a3_ = FDOT2(as_h2(W3), as_h2(c27), a3_); \
        a0_ = FDOT2(as_h2(W4), as_h2(c4),  a0_); \
        a1_ = FDOT2(as_h2(W4), as_h2(c12), a1_); \
        a2_ = FDOT2(as_h2(W4), as_h2(c20), a2_); \
        a3_ = FDOT2(as_h2(W4), as_h2(c28), a3_); \
        a0_ = FDOT2(as_h2(W5), as_h2(c5),  a0_); \
        a1_ = FDOT2(as_h2(W5), as_h2(c13), a1_); \
        a2_ = FDOT2(as_h2(W5), as_h2(c21), a2_); \
        a3_ = FDOT2(as_h2(W5), as_h2(c29), a3_); \
        a0_ = FDOT2(as_h2(W6), as_h2(c6),  a0_); \
        a1_ = FDOT2(as_h2(W6), as_h2(c14), a1_); \
        a2_ = FDOT2(as_h2(W6), as_h2(c22), a2_); \
        a3_ = FDOT2(as_h2(W6), as_h2(c30), a3_); \
        a0_ = FDOT2(as_h2(W7), as_h2(c7),  a0_); \
        a1_ = FDOT2(as_h2(W7), as_h2(c15), a1_); \
        a2_ = FDOT2(as_h2(W7), as_h2(c23), a2_); \
        a3_ = FDOT2(as_h2(W7), as_h2(c31), a3_); \
        float a1x_, a3x_; \
        XCH16F(a1x_, a1_) \
        XCH16F(a3x_, a3_) \
        float V0 = a0_ + a1x_; \
        float V1 = a2_ + a3x_; \
        float Vx; XCH32F(Vx, V1); \
        float sum_ = V0 + Vx; \
        float s0_ = first_lane(sum_); \
        L2 += __log2f(s0_); \
        t = (sum_ * (GK)) * __builtin_amdgcn_rcpf(s0_); \
    } while (0)

#define GPREPM(RK, SV, GOUT) { float ee_ = ((SV) < len) ? (RK) : 0.0f; \
                               float e0_ = first_lane(ee_); \
                               GOUT = __expf(ee_ - e0_ - 4.0f); Lc += e0_ + 4.0f; }

    const float LN2 = 0.69314718055994531f;
    float anchor;

    if (isFwd) {
        // roles 0/1/3: fwd, steps sBase..sBase+126(+127)
        const int sBase = (role == 0) ? 1 : ((role == 1) ? 128 : 256);
        if (role == 0) {
            float sc0 = em[j] + trans[j * TSTRIDE + TT];  // mask[0]==1 always
            anchor = first_lane(sc0) + 4.0f;
            t = __expf(sc0 - anchor);
        } else {
            anchor = 0.0f;
            t = 1.0f;                                     // uniform start
        }
        float r0 = em[(size_t)(sBase + 0) * TT + j], r1 = em[(size_t)(sBase + 1) * TT + j];
        float r2 = em[(size_t)(sBase + 2) * TT + j], r3 = em[(size_t)(sBase + 3) * TT + j];
        float r4 = em[(size_t)(sBase + 4) * TT + j], r5 = em[(size_t)(sBase + 5) * TT + j];
        float r6 = em[(size_t)(sBase + 6) * TT + j], r7 = em[(size_t)(sBase + 7) * TT + j];
        const float* pe = em + (size_t)(sBase + 8) * TT + j;
        int scur = sBase;
        for (int it = 0; it < 15; ++it) {       // 120 steps
            float n0 = pe[0],   n1 = pe[64],  n2 = pe[128], n3 = pe[192];
            float n4 = pe[256], n5 = pe[320], n6 = pe[384], n7 = pe[448];
            pe += 512;
            float g0, g1, g2, g3, g4, g5, g6, g7;
            GPREPM(r0, scur + 0, g0) GPREPM(r1, scur + 1, g1)
            GPREPM(r2, scur + 2, g2) GPREPM(r3, scur + 3, g3)
            GPREPM(r4, scur + 4, g4) GPREPM(r5, scur + 5, g5)
            GPREPM(r6, scur + 6, g6) GPREPM(r7, scur + 7, g7)
            STEPP(g0); STEPP(g1); STEPP(g2); STEPP(g3);
            STEPP(g4); STEPP(g5); STEPP(g6); STEPP(g7);
            scur += 8;
            r0 = n0; r1 = n1; r2 = n2; r3 = n3;
            r4 = n4; r5 = n5; r6 = n6; r7 = n7;
        }
        {   // epilogue: 7 steps (role 0) or 8 steps (roles 1/3)
            float g0, g1, g2, g3, g4, g5, g6;
            GPREPM(r0, scur + 0, g0) GPREPM(r1, scur + 1, g1)
            GPREPM(r2, scur + 2, g2) GPREPM(r3, scur + 3, g3)
            GPREPM(r4, scur + 4, g4) GPREPM(r5, scur + 5, g5)
            GPREPM(r6, scur + 6, g6)
            STEPP(g0); STEPP(g1); STEPP(g2); STEPP(g3);
            STEPP(g4); STEPP(g5); STEPP(g6);
            if (role != 0) {
                float g7x;
                GPREPM(r7, scur + 7, g7x)
                STEPP(g7x);
            }
        }
    } else {
        // roles 2/4/5: bwd, rows sHi..sHi-127 (128 E-applications)
        const int sHi = (role == 2) ? 255 : ((role == 4) ? 383 : 511);
        float q;
        if (role == 5) {
            float u0 = trans[65 * TSTRIDE + j];           // stop vector
            anchor = first_lane(u0) + 4.0f;
            q = __expf(u0 - anchor);
        } else {
            anchor = 0.0f;
            q = 1.0f;                                     // uniform start
        }
        float r0 = em[(size_t)(sHi - 0) * TT + j], r1 = em[(size_t)(sHi - 1) * TT + j];
        float r2 = em[(size_t)(sHi - 2) * TT + j], r3 = em[(size_t)(sHi - 3) * TT + j];
        float r4 = em[(size_t)(sHi - 4) * TT + j], r5 = em[(size_t)(sHi - 5) * TT + j];
        float r6 = em[(size_t)(sHi - 6) * TT + j], r7 = em[(size_t)(sHi - 7) * TT + j];
        const float* pe = em + (size_t)(sHi - 8) * TT + j;
        int scur = sHi;
        {   // init: fold diag at row sHi
            float h0i;
            GPREPM(r0, sHi, h0i)
            t = q * h0i;
        }
        for (int it = 0; it < 15; ++it) {       // 120 steps
            float n0 = pe[0],    n1 = pe[-64],  n2 = pe[-128], n3 = pe[-192];
            float n4 = pe[-256], n5 = pe[-320], n6 = pe[-384], n7 = pe[-448];
            pe -= 512;
            float g1, g2, g3, g4, g5, g6, g7, g8;
            GPREPM(r1, scur - 1, g1) GPREPM(r2, scur - 2, g2)
            GPREPM(r3, scur - 3, g3) GPREPM(r4, scur - 4, g4)
            GPREPM(r5, scur - 5, g5) GPREPM(r6, scur - 6, g6)
            GPREPM(r7, scur - 7, g7) GPREPM(n0, scur - 8, g8)
            STEPP(g1); STEPP(g2); STEPP(g3); STEPP(g4);
            STEPP(g5); STEPP(g6); STEPP(g7); STEPP(g8);
            scur -= 8;
            r0 = n0; r1 = n1; r2 = n2; r3 = n3;
            r4 = n4; r5 = n5; r6 = n6; r7 = n7;
        }
        {   // epilogue: rows scur-1..scur-7 then final E with g=1
            float g1, g2, g3, g4, g5, g6, g7;
            GPREPM(r1, scur - 1, g1) GPREPM(r2, scur - 2, g2)
            GPREPM(r3, scur - 3, g3) GPREPM(r4, scur - 4, g4)
            GPREPM(r5, scur - 5, g5) GPREPM(r6, scur - 6, g6)
            GPREPM(r7, scur - 7, g7)
            STEPP(g1); STEPP(g2); STEPP(g3); STEPP(g4);
            STEPP(g5); STEPP(g6); STEPP(g7); STEPP(1.0f);
        }
    }
#undef STEPP
#undef GPREPM
#undef XCH32F
#undef XCH16F

    ws_state[(size_t)b * 384 + role * 64 + j] = anchor + Lc + L2 * LN2 + __logf(t);
}

// Per-batch wave: rank-1 composition + gold path.
// logZ = LSE(d+Cu) + LSE(CTu+Bu) + LSE(BTu+a) - LSE(Cu) - LSE(Bu)
__global__ __launch_bounds__(64) void crf_combine_kernel(
    const float* __restrict__ emissions,
    const int*   __restrict__ tags,
    const float* __restrict__ mask,
    const float* __restrict__ trans,
    const float* __restrict__ ws_state,
    float* __restrict__ diff_out)
{
    const int b = blockIdx.x;
    const int j = threadIdx.x;
    const float* em = emissions + (size_t)b * SS * TT;
    const float* mk = mask + (size_t)b * SS;
    const float* W = ws_state + (size_t)b * 384;

    const float la  = W[0 * 64 + j];   // A-fwd  (exact)
    const float lBu = W[1 * 64 + j];   // B fwd-from-ones
    const float lBT = W[2 * 64 + j];   // B bwd-from-ones
    const float lCu = W[3 * 64 + j];   // C fwd-from-ones
    const float lCT = W[4 * 64 + j];   // C bwd-from-ones
    const float ld  = W[5 * 64 + j];   // D-bwd  (exact)

#define WLSE(X, OUT) { float x_ = (X); float m_ = x_; \
        _Pragma("unroll") \
        for (int off = 32; off; off >>= 1) m_ = fmaxf(m_, __shfl_xor(m_, off)); \
        float e_ = __expf(x_ - m_); \
        _Pragma("unroll") \
        for (int off = 32; off; off >>= 1) e_ += __shfl_xor(e_, off); \
        OUT = m_ + __logf(e_); }

    float z1, z2, z3, z4, z5;
    WLSE(ld + lCu, z1)
    WLSE(lCT + lBu, z2)
    WLSE(lBT + la, z3)
    WLSE(lCu, z4)
    WLSE(lBu, z5)
#undef WLSE
    const float zres = z1 + z2 + z3 - z4 - z5;

    float msum = 0.f;
    #pragma unroll
    for (int t = 0; t < 8; ++t) msum += mk[j + 64 * t];
    #pragma unroll
    for (int off = 32; off; off >>= 1) msum += __shfl_xor(msum, off);
    const int len = (int)(first_lane(msum) + 0.5f);

    const int* tg = tags + (size_t)b * SS;
    float acc = 0.f;
    for (int s = j; s < SS; s += 64) {
        if (s < len) {
            if (s > 0) {
                int curr = tg[s], prev = tg[s - 1];
                acc += trans[curr * TSTRIDE + prev] + em[s * TT + curr];
            } else {
                int t0_ = tg[0];
                acc += em[t0_] + trans[t0_ * TSTRIDE + TT];
            }
        }
    }
    #pragma unroll
    for (int off = 32; off; off >>= 1) acc += __shfl_xor(acc, off);
    if (j == 0) {
        int last = tg[len - 1];
        acc += trans[65 * TSTRIDE + last];
        diff_out[b] = zres - acc;
    }
}

__global__ __launch_bounds__(256) void crf_final_kernel(
    const float* __restrict__ diff,
    float* __restrict__ out)
{
    __shared__ float sdata[4];
    int t = threadIdx.x;
    float v = 0.f;
    for (int i = t; i < BB; i += 256) v += diff[i];
    #pragma unroll
    for (int off = 32; off; off >>= 1) v += __shfl_xor(v, off);
    if ((t & 63) == 0) sdata[t >> 6] = v;
    __syncthreads();
    if (t == 0) out[0] = (sdata[0] + sdata[1] + sdata[2] + sdata[3]) * (1.0f / BB);
}

extern "C" void kernel_launch(void* const* d_in, const int* in_sizes, int n_in,
                              void* d_out, int out_size, void* d_ws, size_t ws_size,
                              hipStream_t stream) {
    const float* emissions = (const float*)d_in[0];
    const int*   tags      = (const int*)d_in[1];
    const float* mask      = (const float*)d_in[2];
    const float* trans     = (const float*)d_in[3];
    float* out  = (float*)d_out;
    float* ws_state = (float*)d_ws;             // 512*384 floats
    float* diff = ws_state + (size_t)BB * 384;  // 512 floats

    crf_scan6_kernel<<<6 * BB, 64, 0, stream>>>(emissions, mask, trans, ws_state);
    crf_combine_kernel<<<BB, 64, 0, stream>>>(emissions, tags, mask, trans,
                                              ws_state, diff);
    crf_final_kernel<<<1, 256, 0, stream>>>(diff, out);
}

// Round 17
// 80.595 us; speedup vs baseline: 1.2796x; 1.2796x over previous
//
#include <hip/hip_runtime.h>

#define BB 512
#define SS 512
#define TT 64
#define TSTRIDE 66   // transitions is (66,66)

typedef _Float16 h2 __attribute__((ext_vector_type(2)));
typedef int i2v __attribute__((ext_vector_type(2)));

static __device__ __forceinline__ float first_lane(float v) {
    return __int_as_float(__builtin_amdgcn_readfirstlane(__float_as_int(v)));
}
static __device__ __forceinline__ unsigned pk_f16(float a, float b) {
    return __builtin_bit_cast(unsigned, __builtin_amdgcn_cvt_pkrtz(a, b));
}
static __device__ __forceinline__ h2 as_h2(unsigned u) {
    return __builtin_bit_cast(h2, u);
}
static __device__ __forceinline__ unsigned bperm(int addr, unsigned v) {
    return (unsigned)__builtin_amdgcn_ds_bpermute(addr, (int)v);
}
static __device__ __forceinline__ float swz16f(float v) {   // value from lane^16
    return __int_as_float(__builtin_amdgcn_ds_swizzle(__float_as_int(v), 0x401F));
}
#define FDOT2(a, b, c) __builtin_amdgcn_fdot2((a), (b), (c), false)
#define DPPF(v, ctrl) __int_as_float(__builtin_amdgcn_mov_dpp(__float_as_int(v), (ctrl), 0xF, 0xF, true))
#define DPPU(v, ctrl) ((unsigned)__builtin_amdgcn_mov_dpp((int)(v), (ctrl), 0xF, 0xF, true))

#define DO32(F) F(0) F(1) F(2) F(3) F(4) F(5) F(6) F(7) \
                F(8) F(9) F(10) F(11) F(12) F(13) F(14) F(15) \
                F(16) F(17) F(18) F(19) F(20) F(21) F(22) F(23) \
                F(24) F(25) F(26) F(27) F(28) F(29) F(30) F(31)

// R17 = R16 (rank-1 4-segment MITM, absmax-0 verified) with the occupancy
// cap FIXED: waves_per_eu(1,3) instead of (1,1). R16's (1,1) serialized the
// 3072 waves into 3 cohorts (Occupancy stayed 10%) -> 108us. At max=3 the
// RA budget is ~170 VGPR >= the 132 needed (no R2-style spill), LDS
// 12x8KB = 96KB/CU < 160KB, and all 6 chains/batch run concurrently at
// 3 waves/SIMD.
// Segments: A = steps 1..127 exact from v0; B = 128..255 and C = 256..383
// rank-1 compressed (Birkhoff contraction ~0.1/step => exact in f32):
// M ~ (Mu)(M^T u)^T/(u^T M u); D = 511..384 exact from stop.
// logZ = LSE(d+Cu) + LSE(CTu+Bu) + LSE(BTu+a) - LSE(Cu) - LSE(Bu).
// Step skeleton = R15: product-form recurrence (exp/log off critical path),
// blocked dots (tl={0,2,7,5,15,13,8,10}), VALU reduce (perm16+perm32).
// roles: 0=a(fwd,v0) 1=Bu(fwd,u) 3=Cu(fwd,u) | 2=BTu(bwd,u) 4=CTu(bwd,u)
//        5=d(bwd,stop)
__global__ __launch_bounds__(64)
__attribute__((amdgpu_waves_per_eu(1, 3)))
void crf_scan6_kernel(
    const float* __restrict__ emissions,   // [B,S,T]
    const float* __restrict__ mask,        // [B,S]
    const float* __restrict__ trans,       // [66,66]
    float* __restrict__ ws_state)          // [B][6][64] log-form vectors
{
    __shared__ unsigned EQ[32][64];        // 8 KB E-fragment staging

    const int blk  = blockIdx.x;
    const int b    = blk / 6;
    const int role = blk - 6 * b;
    const bool isFwd = (role == 0) | (role == 1) | (role == 3);
    const int j   = threadIdx.x;   // 0..63
    const bool lo32  = (j < 32);
    const bool odd16 = (j & 16) != 0;
    const int a32v = ((j ^ 32) << 2);      // bpermute fallback address

    const float* em = emissions + (size_t)b * SS * TT;
    const float* mk = mask + (size_t)b * SS;

    // ---- E fragments, pre-permuted (R11-verified layout) ----
    {
        const int tl[8] = {0, 2, 7, 5, 15, 13, 8, 10};
        #pragma unroll
        for (int w = 0; w < 32; ++w) {
            int m = w >> 3, k = w & 7;
            int y0 = j ^ tl[k];
            int y1 = y0 ^ 1;
            int x  = j ^ (m << 4);
            if (isFwd)      // fwd: M[x][y] = trans[y*66 + x]
                EQ[w][j] = pk_f16(__expf(trans[y0 * TSTRIDE + x]),
                                  __expf(trans[y1 * TSTRIDE + x]));
            else            // bwd: M[x][y] = trans[x*66 + y]
                EQ[w][j] = pk_f16(__expf(trans[x * TSTRIDE + y0]),
                                  __expf(trans[x * TSTRIDE + y1]));
        }
    }
    __syncthreads();

#define CDECL(K) const unsigned c##K = EQ[K][j];
    DO32(CDECL)
#undef CDECL

#if defined(__has_builtin) && __has_builtin(__builtin_amdgcn_permlane32_swap)
#define XCH32F(DST, SRC) { i2v r_ = __builtin_amdgcn_permlane32_swap( \
                               __float_as_int(SRC), __float_as_int(SRC), false, false); \
                           DST = __int_as_float(lo32 ? r_.y : r_.x); }
#else
#define XCH32F(DST, SRC) { DST = __int_as_float((int)bperm(a32v, (unsigned)__float_as_int(SRC))); }
#endif

#if defined(__has_builtin) && __has_builtin(__builtin_amdgcn_permlane16_swap)
#define XCH16F(DST, SRC) { i2v r_ = __builtin_amdgcn_permlane16_swap( \
                               __float_as_int(SRC), __float_as_int(SRC), false, false); \
                           DST = __int_as_float(odd16 ? r_.x : r_.y); }
#else
#define XCH16F(DST, SRC) { DST = swz16f(SRC); }
#endif

    // len (len in [256,512]; masked GPREP is a no-op for always-valid ranges)
    float msum = 0.f;
    #pragma unroll
    for (int tq = 0; tq < 8; ++tq) msum += mk[j + 64 * tq];
    #pragma unroll
    for (int off = 32; off; off >>= 1) msum += __shfl_xor(msum, off);
    const int len = (int)(first_lane(msum) + 0.5f);

    float t, L2 = 0.f, Lc = 0.f;

#define STEPP(GK) do { \
        float pn_ = DPPF(t, 0xB1); \
        unsigned W0 = pk_f16(t, pn_); \
        unsigned W1 = DPPU(W0, 0x4E); \
        unsigned W2 = DPPU(W0, 0x141); \
        unsigned W3 = DPPU(W1, 0x141); \
        unsigned W4 = DPPU(W0, 0x140); \
        unsigned W5 = DPPU(W1, 0x140); \
        unsigned W6 = DPPU(W4, 0x141); \
        unsigned W7 = DPPU(W5, 0x141); \
        float a0_ = 0.f, a1_ = 0.f, a2_ = 0.f, a3_ = 0.f; \
        a0_ = FDOT2(as_h2(W0), as_h2(c0),  a0_); \
        a1_ = FDOT2(as_h2(W0), as_h2(c8),  a1_); \
        a2_ = FDOT2(as_h2(W0), as_h2(c16), a2_); \
        a3_ = FDOT2(as_h2(W0), as_h2(c24), a3_); \
        a0_ = FDOT2(as_h2(W1), as_h2(c1),  a0_); \
        a1_ = FDOT2(as_h2(W1), as_h2(c9),  a1_); \
        a2_ = FDOT2(as_h2(W1), as_h2(c17), a2_); \
        a3_ = FDOT2(as_h2(W1), as_h2(c25), a3_); \
        a0_ = FDOT2(as_h2(W2), as_h2(c2),  a0_); \
        a1_ = FDOT2(as_h2(W2), as_h2(c10), a1_); \
        a2_ = FDOT2(as_h2(W2), as_h2(c18), a2_); \
        a3_ = FDOT2(as_h2(W2), as_h2(c26), a3_); \
        a0_ = FDOT2(as_h2(W3), as_h2(c3),  a0_); \
        a1_ = FDOT2(as_h2(W3), as_h2(c11), a1_); \
        a2_ = FDOT2(as_h2(W3), as_h2(c19), a2_); \
        a3_ = FDOT2(as_h2(W3), as_h2(c27), a3_); \
        a0_ = FDOT2(as_h2(W4), as_h2(c4),  a0_); \
        a1_ = FDOT2(as_h2(W4), as_h2(c12), a1_); \
        a2_ = FDOT2(as_h2(W4), as_h2(c20), a2_); \
        a3_ = FDOT2(as_h2(W4), as_h2(c28), a3_); \
        a0_ = FDOT2(as_h2(W5), as_h2(c5),  a0_); \
        a1_ = FDOT2(as_h2(W5), as_h2(c13), a1_); \
        a2_ = FDOT2(as_h2(W5), as_h2(c21), a2_); \
        a3_ = FDOT2(as_h2(W5), as_h2(c29), a3_); \
        a0_ = FDOT2(as_h2(W6), as_h2(c6),  a0_); \
        a1_ = FDOT2(as_h2(W6), as_h2(c14), a1_); \
        a2_ = FDOT2(as_h2(W6), as_h2(c22), a2_); \
        a3_ = FDOT2(as_h2(W6), as_h2(c30), a3_); \
        a0_ = FDOT2(as_h2(W7), as_h2(c7),  a0_); \
        a1_ = FDOT2(as_h2(W7), as_h2(c15), a1_); \
        a2_ = FDOT2(as_h2(W7), as_h2(c23), a2_); \
        a3_ = FDOT2(as_h2(W7), as_h2(c31), a3_); \
        float a1x_, a3x_; \
        XCH16F(a1x_, a1_) \
        XCH16F(a3x_, a3_) \
        float V0 = a0_ + a1x_; \
        float V1 = a2_ + a3x_; \
        float Vx; XCH32F(Vx, V1); \
        float sum_ = V0 + Vx; \
        float s0_ = first_lane(sum_); \
        L2 += __log2f(s0_); \
        t = (sum_ * (GK)) * __builtin_amdgcn_rcpf(s0_); \
    } while (0)

#define GPREPM(RK, SV, GOUT) { float ee_ = ((SV) < len) ? (RK) : 0.0f; \
                               float e0_ = first_lane(ee_); \
                               GOUT = __expf(ee_ - e0_ - 4.0f); Lc += e0_ + 4.0f; }

    const float LN2 = 0.69314718055994531f;
    float anchor;

    if (isFwd) {
        // roles 0/1/3: fwd, steps sBase..sBase+126(+127)
        const int sBase = (role == 0) ? 1 : ((role == 1) ? 128 : 256);
        if (role == 0) {
            float sc0 = em[j] + trans[j * TSTRIDE + TT];  // mask[0]==1 always
            anchor = first_lane(sc0) + 4.0f;
            t = __expf(sc0 - anchor);
        } else {
            anchor = 0.0f;
            t = 1.0f;                                     // uniform start
        }
        float r0 = em[(size_t)(sBase + 0) * TT + j], r1 = em[(size_t)(sBase + 1) * TT + j];
        float r2 = em[(size_t)(sBase + 2) * TT + j], r3 = em[(size_t)(sBase + 3) * TT + j];
        float r4 = em[(size_t)(sBase + 4) * TT + j], r5 = em[(size_t)(sBase + 5) * TT + j];
        float r6 = em[(size_t)(sBase + 6) * TT + j], r7 = em[(size_t)(sBase + 7) * TT + j];
        const float* pe = em + (size_t)(sBase + 8) * TT + j;
        int scur = sBase;
        for (int it = 0; it < 15; ++it) {       // 120 steps
            float n0 = pe[0],   n1 = pe[64],  n2 = pe[128], n3 = pe[192];
            float n4 = pe[256], n5 = pe[320], n6 = pe[384], n7 = pe[448];
            pe += 512;
            float g0, g1, g2, g3, g4, g5, g6, g7;
            GPREPM(r0, scur + 0, g0) GPREPM(r1, scur + 1, g1)
            GPREPM(r2, scur + 2, g2) GPREPM(r3, scur + 3, g3)
            GPREPM(r4, scur + 4, g4) GPREPM(r5, scur + 5, g5)
            GPREPM(r6, scur + 6, g6) GPREPM(r7, scur + 7, g7)
            STEPP(g0); STEPP(g1); STEPP(g2); STEPP(g3);
            STEPP(g4); STEPP(g5); STEPP(g6); STEPP(g7);
            scur += 8;
            r0 = n0; r1 = n1; r2 = n2; r3 = n3;
            r4 = n4; r5 = n5; r6 = n6; r7 = n7;
        }
        {   // epilogue: 7 steps (role 0) or 8 steps (roles 1/3)
            float g0, g1, g2, g3, g4, g5, g6;
            GPREPM(r0, scur + 0, g0) GPREPM(r1, scur + 1, g1)
            GPREPM(r2, scur + 2, g2) GPREPM(r3, scur + 3, g3)
            GPREPM(r4, scur + 4, g4) GPREPM(r5, scur + 5, g5)
            GPREPM(r6, scur + 6, g6)
            STEPP(g0); STEPP(g1); STEPP(g2); STEPP(g3);
            STEPP(g4); STEPP(g5); STEPP(g6);
            if (role != 0) {
                float g7x;
                GPREPM(r7, scur + 7, g7x)
                STEPP(g7x);
            }
        }
    } else {
        // roles 2/4/5: bwd, rows sHi..sHi-127 (128 E-applications)
        const int sHi = (role == 2) ? 255 : ((role == 4) ? 383 : 511);
        float q;
        if (role == 5) {
            float u0 = trans[65 * TSTRIDE + j];           // stop vector
            anchor = first_lane(u0) + 4.0f;
            q = __expf(u0 - anchor);
        } else {
            anchor = 0.0f;
            q = 1.0f;                                     // uniform start
        }
        float r0 = em[(size_t)(sHi - 0) * TT + j], r1 = em[(size_t)(sHi - 1) * TT + j];
        float r2 = em[(size_t)(sHi - 2) * TT + j], r3 = em[(size_t)(sHi - 3) * TT + j];
        float r4 = em[(size_t)(sHi - 4) * TT + j], r5 = em[(size_t)(sHi - 5) * TT + j];
        float r6 = em[(size_t)(sHi - 6) * TT + j], r7 = em[(size_t)(sHi - 7) * TT + j];
        const float* pe = em + (size_t)(sHi - 8) * TT + j;
        int scur = sHi;
        {   // init: fold diag at row sHi
            float h0i;
            GPREPM(r0, sHi, h0i)
            t = q * h0i;
        }
        for (int it = 0; it < 15; ++it) {       // 120 steps
            float n0 = pe[0],    n1 = pe[-64],  n2 = pe[-128], n3 = pe[-192];
            float n4 = pe[-256], n5 = pe[-320], n6 = pe[-384], n7 = pe[-448];
            pe -= 512;
            float g1, g2, g3, g4, g5, g6, g7, g8;
            GPREPM(r1, scur - 1, g1) GPREPM(r2, scur - 2, g2)
            GPREPM(r3, scur - 3, g3) GPREPM(r4, scur - 4, g4)
            GPREPM(r5, scur - 5, g5) GPREPM(r6, scur - 6, g6)
            GPREPM(r7, scur - 7, g7) GPREPM(n0, scur - 8, g8)
            STEPP(g1); STEPP(g2); STEPP(g3); STEPP(g4);
            STEPP(g5); STEPP(g6); STEPP(g7); STEPP(g8);
            scur -= 8;
            r0 = n0; r1 = n1; r2 = n2; r3 = n3;
            r4 = n4; r5 = n5; r6 = n6; r7 = n7;
        }
        {   // epilogue: rows scur-1..scur-7 then final E with g=1
            float g1, g2, g3, g4, g5, g6, g7;
            GPREPM(r1, scur - 1, g1) GPREPM(r2, scur - 2, g2)
            GPREPM(r3, scur - 3, g3) GPREPM(r4, scur - 4, g4)
            GPREPM(r5, scur - 5, g5) GPREPM(r6, scur - 6, g6)
            GPREPM(r7, scur - 7, g7)
            STEPP(g1); STEPP(g2); STEPP(g3); STEPP(g4);
            STEPP(g5); STEPP(g6); STEPP(g7); STEPP(1.0f);
        }
    }
#undef STEPP
#undef GPREPM
#undef XCH32F
#undef XCH16F

    ws_state[(size_t)b * 384 + role * 64 + j] = anchor + Lc + L2 * LN2 + __logf(t);
}

// Per-batch wave: rank-1 composition + gold path.
// logZ = LSE(d+Cu) + LSE(CTu+Bu) + LSE(BTu+a) - LSE(Cu) - LSE(Bu)
__global__ __launch_bounds__(64) void crf_combine_kernel(
    const float* __restrict__ emissions,
    const int*   __restrict__ tags,
    const float* __restrict__ mask,
    const float* __restrict__ trans,
    const float* __restrict__ ws_state,
    float* __restrict__ diff_out)
{
    const int b = blockIdx.x;
    const int j = threadIdx.x;
    const float* em = emissions + (size_t)b * SS * TT;
    const float* mk = mask + (size_t)b * SS;
    const float* W = ws_state + (size_t)b * 384;

    const float la  = W[0 * 64 + j];   // A-fwd  (exact)
    const float lBu = W[1 * 64 + j];   // B fwd-from-ones
    const float lBT = W[2 * 64 + j];   // B bwd-from-ones
    const float lCu = W[3 * 64 + j];   // C fwd-from-ones
    const float lCT = W[4 * 64 + j];   // C bwd-from-ones
    const float ld  = W[5 * 64 + j];   // D-bwd  (exact)

#define WLSE(X, OUT) { float x_ = (X); float m_ = x_; \
        _Pragma("unroll") \
        for (int off = 32; off; off >>= 1) m_ = fmaxf(m_, __shfl_xor(m_, off)); \
        float e_ = __expf(x_ - m_); \
        _Pragma("unroll") \
        for (int off = 32; off; off >>= 1) e_ += __shfl_xor(e_, off); \
        OUT = m_ + __logf(e_); }

    float z1, z2, z3, z4, z5;
    WLSE(ld + lCu, z1)
    WLSE(lCT + lBu, z2)
    WLSE(lBT + la, z3)
    WLSE(lCu, z4)
    WLSE(lBu, z5)
#undef WLSE
    const float zres = z1 + z2 + z3 - z4 - z5;

    float msum = 0.f;
    #pragma unroll
    for (int t = 0; t < 8; ++t) msum += mk[j + 64 * t];
    #pragma unroll
    for (int off = 32; off; off >>= 1) msum += __shfl_xor(msum, off);
    const int len = (int)(first_lane(msum) + 0.5f);

    const int* tg = tags + (size_t)b * SS;
    float acc = 0.f;
    for (int s = j; s < SS; s += 64) {
        if (s < len) {
            if (s > 0) {
                int curr = tg[s], prev = tg[s - 1];
                acc += trans[curr * TSTRIDE + prev] + em[s * TT + curr];
            } else {
                int t0_ = tg[0];
                acc += em[t0_] + trans[t0_ * TSTRIDE + TT];
            }
        }
    }
    #pragma unroll
    for (int off = 32; off; off >>= 1) acc += __shfl_xor(acc, off);
    if (j == 0) {
        int last = tg[len - 1];
        acc += trans[65 * TSTRIDE + last];
        diff_out[b] = zres - acc;
    }
}

__global__ __launch_bounds__(256) void crf_final_kernel(
    const float* __restrict__ diff,
    float* __restrict__ out)
{
    __shared__ float sdata[4];
    int t = threadIdx.x;
    float v = 0.f;
    for (int i = t; i < BB; i += 256) v += diff[i];
    #pragma unroll
    for (int off = 32; off; off >>= 1) v += __shfl_xor(v, off);
    if ((t & 63) == 0) sdata[t >> 6] = v;
    __syncthreads();
    if (t == 0) out[0] = (sdata[0] + sdata[1] + sdata[2] + sdata[3]) * (1.0f / BB);
}

extern "C" void kernel_launch(void* const* d_in, const int* in_sizes, int n_in,
                              void* d_out, int out_size, void* d_ws, size_t ws_size,
                              hipStream_t stream) {
    const float* emissions = (const float*)d_in[0];
    const int*   tags      = (const int*)d_in[1];
    const float* mask      = (const float*)d_in[2];
    const float* trans     = (const float*)d_in[3];
    float* out  = (float*)d_out;
    float* ws_state = (float*)d_ws;             // 512*384 floats
    float* diff = ws_state + (size_t)BB * 384;  // 512 floats

    crf_scan6_kernel<<<6 * BB, 64, 0, stream>>>(emissions, mask, trans, ws_state);
    crf_combine_kernel<<<BB, 64, 0, stream>>>(emissions, tags, mask, trans,
                                              ws_state, diff);
    crf_final_kernel<<<1, 256, 0, stream>>>(diff, out);
}